// Round 5
// baseline (603.431 us; speedup 1.0000x reference)
//
#include <hip/hip_runtime.h>
#include <cstdint>
#include <cstddef>

#define HH 96
#define WW 96
#define NN 8
#define CIN 512
#define CMID 256
#define CO2 576

typedef __attribute__((ext_vector_type(4))) float f32x4;
typedef __attribute__((ext_vector_type(8))) short short8;

static __device__ __forceinline__ unsigned short f2bf(float f) {
    unsigned int u = __float_as_uint(f);
    u += 0x7fffu + ((u >> 16) & 1u);
    return (unsigned short)(u >> 16);
}

// w1 (256,512,3,3) OIHW fp32 -> w1p: 144 slabs [(cc,tap)] of 8192 shorts:
//   i = slab*8192 + co16*512 + lane*8 + e ; co = co16*16 + (lane&15),
//   ci = cc*32 + (lane>>4)*8 + e   (wave af load = 1KB contiguous)
// w2 (576,256,1,1) fp32 -> w2p: [kc(8)][tc(36)][lane(64)][e(8)] same recipe
__global__ __launch_bounds__(256) void prep_w_kernel(
    const float* __restrict__ w1, const float* __restrict__ w2,
    unsigned short* __restrict__ w1p, unsigned short* __restrict__ w2p)
{
    size_t i = (size_t)blockIdx.x * 256 + threadIdx.x;
    if (i < (size_t)144 * 8192) {
        int sb = (int)(i >> 13);
        int r13 = (int)(i & 8191);
        int co16 = r13 >> 9;
        int g = (r13 >> 7) & 3;
        int sl = (r13 >> 3) & 15;
        int e = (int)(i & 7);
        int cc = sb / 9, tap = sb % 9;
        int co = co16 * 16 + sl;
        int ci = cc * 32 + g * 8 + e;
        w1p[i] = f2bf(w1[((size_t)co * CIN + ci) * 9 + tap]);
    }
    if (i < (size_t)8 * 36 * 64 * 8) {           // 147456
        int idx = (int)i;
        int e = idx & 7;
        int ln = (idx >> 3) & 63;
        int tc = (idx >> 9) % 36;
        int kc = (idx >> 9) / 36;
        int sl = ln & 15, g = ln >> 4;
        int co = tc * 16 + sl;
        int ci = kc * 32 + g * 8 + e;
        w2p[idx] = f2bf(w2[(size_t)co * CMID + ci]);
    }
}

// feature (N,512,96,96) fp32 -> featT [N][H][W][512] bf16
__global__ __launch_bounds__(256) void transpose_kernel(
    const float* __restrict__ f, unsigned short* __restrict__ ft)
{
    __shared__ float t[96 * 65];
    const int tid = threadIdx.x;
    const int b = blockIdx.x;
    const int n = b / HH, h = b % HH;
    for (int cb = 0; cb < 8; ++cb) {
        __syncthreads();
        #pragma unroll
        for (int it = 0; it < 24; ++it) {
            int idx = tid + it * 256;
            int cl = idx / 96, w = idx - cl * 96;
            t[w * 65 + cl] = f[(((size_t)n * CIN + cb * 64 + cl) * HH + h) * WW + w];
        }
        __syncthreads();
        #pragma unroll
        for (int it = 0; it < 24; ++it) {
            int idx = tid + it * 256;
            int w = idx >> 6, cl = idx & 63;
            ft[(((size_t)n * HH + h) * WW + w) * CIN + cb * 64 + cl] = f2bf(t[w * 65 + cl]);
        }
    }
}

// conv1 v5: 3x3, 512->256, bias+ReLU. One block per (n,h), 4 waves.
// A: registers, direct from fragment-ordered w1p (1KB contiguous per load),
//    double-buffered with compile-time parity (cc-pair loop).
// B: LDS 4-slot XOR layout, double-buffered, issue-early/write-late,
//    ONE barrier per 32-ci chunk (16 barriers total).
__global__ __launch_bounds__(256) void conv1_kernel(
    const unsigned short* __restrict__ featT,
    const unsigned short* __restrict__ w1p,
    const float* __restrict__ b1,
    unsigned short* __restrict__ x)
{
    __shared__ unsigned short fsB[2][3 * 98 * 32];   // 2 x 18816 B
    const int tid = threadIdx.x;
    int bid = blockIdx.x;
    bid = (bid & 7) * 96 + (bid >> 3);               // XCD swizzle (768 = 8*96)
    const int n = bid / HH, h = bid % HH;
    const int wave = tid >> 6, lane = tid & 63;      // wave = co-group
    const int g = lane >> 4, sl = lane & 15;

    f32x4 acc[6][4];
    #pragma unroll
    for (int i = 0; i < 6; ++i)
        #pragma unroll
        for (int j = 0; j < 4; ++j) acc[i][j] = (f32x4)0.0f;

    // B staging maps: 1152 chunks = [seg(12)=r*4+s][w(96)], 4.5 per thread
    bool act[5], vld[5];
    int gB[5], lB[5];
    #pragma unroll
    for (int k = 0; k < 5; ++k) {
        int l = tid + k * 256;
        act[k] = (l < 1152);
        int ll = act[k] ? l : 0;
        int seg = ll / 96, w = ll - seg * 96;
        int r = seg >> 2, s = seg & 3;
        int row = h - 1 + r;
        vld[k] = act[k] && ((unsigned)row < HH);
        int rs = ((unsigned)row < HH) ? row : 0;
        gB[k] = ((n * HH + rs) * WW + w) * CIN + s * 8;
        int lw = w + 1;
        lB[k] = ((r * 98 + lw) * 4 + (s ^ (lw & 3))) * 8;
    }

    short8 bstg[5];
    short8 af0[4], af1[4];

    // prologue: B chunk 0 -> fsB[0]; halo zeros both bufs; af slab 0 -> af0
    #pragma unroll
    for (int k = 0; k < 5; ++k) {
        short8 v = (short8)0;
        if (vld[k]) v = *reinterpret_cast<const short8*>(&featT[gB[k]]);
        bstg[k] = v;
    }
    if (tid < 48) {
        int bb = tid / 24, rem = tid - bb * 24;
        int r = rem >> 3, c2 = (rem >> 2) & 1, s = rem & 3;
        int lw = c2 ? 97 : 0;
        *reinterpret_cast<short8*>(
            &fsB[bb][((r * 98 + lw) * 4 + (s ^ (lw & 3))) * 8]) = (short8)0;
    }
    #pragma unroll
    for (int tc = 0; tc < 4; ++tc)
        af0[tc] = *reinterpret_cast<const short8*>(
            &w1p[(size_t)(((wave * 4 + tc) * 64 + lane) * 8)]);
    #pragma unroll
    for (int k = 0; k < 5; ++k)
        if (act[k]) *reinterpret_cast<short8*>(&fsB[0][lB[k]]) = bstg[k];
    __syncthreads();

    auto afload = [&](short8 (&af)[4], int sb1) {
        const unsigned short* ap = &w1p[(size_t)sb1 * 8192];
        #pragma unroll
        for (int tc = 0; tc < 4; ++tc)
            af[tc] = *reinterpret_cast<const short8*>(
                &ap[((wave * 4 + tc) * 64 + lane) * 8]);
    };
    auto compute = [&](short8 (&af)[4], int par, int ki, int kj) {
        #pragma unroll
        for (int ts = 0; ts < 6; ++ts) {
            int lw = ts * 16 + sl + kj;
            short8 bf = *reinterpret_cast<const short8*>(
                &fsB[par][((ki * 98 + lw) * 4 + (g ^ (lw & 3))) * 8]);
            #pragma unroll
            for (int tc = 0; tc < 4; ++tc)
                acc[ts][tc] = __builtin_amdgcn_mfma_f32_16x16x32_bf16(
                    af[tc], bf, acc[ts][tc], 0, 0, 0);
        }
    };

    for (int ccp = 0; ccp < 8; ++ccp) {
        #pragma unroll
        for (int par = 0; par < 2; ++par) {
            const int cc = ccp * 2 + par;
            // issue next B chunk early (9 taps of MFMA cover the latency)
            if (cc < 15) {
                #pragma unroll
                for (int k = 0; k < 5; ++k) {
                    short8 v = (short8)0;
                    if (vld[k]) v = *reinterpret_cast<const short8*>(
                        &featT[gB[k] + (cc + 1) * 32]);
                    bstg[k] = v;
                }
            }
            #pragma unroll
            for (int tap = 0; tap < 9; ++tap) {
                const int sbr = cc * 9 + tap;
                const int ki = tap / 3, kj = tap % 3;
                if (((par + tap) & 1) == 0) {
                    if (sbr < 143) afload(af1, sbr + 1);
                    compute(af0, par, ki, kj);
                } else {
                    if (sbr < 143) afload(af0, sbr + 1);
                    compute(af1, par, ki, kj);
                }
            }
            // write-late: next chunk into the other buffer, single barrier
            if (cc < 15) {
                #pragma unroll
                for (int k = 0; k < 5; ++k)
                    if (act[k])
                        *reinterpret_cast<short8*>(&fsB[par ^ 1][lB[k]]) = bstg[k];
                __syncthreads();
            }
        }
    }

    // epilogue: bias + ReLU -> bf16 x[n][h][w][co]
    const size_t rowbase = ((size_t)n * HH + h);
    #pragma unroll
    for (int ts = 0; ts < 6; ++ts) {
        int sp = ts * 16 + sl;
        unsigned short* xp = &x[(rowbase * WW + sp) * CMID];
        #pragma unroll
        for (int tc = 0; tc < 4; ++tc) {
            int co0 = wave * 64 + tc * 16 + g * 4;
            const float4 bb = *reinterpret_cast<const float4*>(&b1[co0]);
            float v0 = acc[ts][tc][0] + bb.x;
            float v1 = acc[ts][tc][1] + bb.y;
            float v2 = acc[ts][tc][2] + bb.z;
            float v3 = acc[ts][tc][3] + bb.w;
            v0 = v0 > 0.f ? v0 : 0.f;
            v1 = v1 > 0.f ? v1 : 0.f;
            v2 = v2 > 0.f ? v2 : 0.f;
            v3 = v3 > 0.f ? v3 : 0.f;
            ushort4 st;
            st.x = f2bf(v0); st.y = f2bf(v1); st.z = f2bf(v2); st.w = f2bf(v3);
            *reinterpret_cast<ushort4*>(&xp[co0]) = st;
        }
    }
}

// conv2 (1x1, 256->576) + bias*0.25 + softmax over 9 taps + flow assembly
// af now from fragment-ordered w2p (1KB contiguous per wave load).
__global__ __launch_bounds__(384) void conv2_kernel(
    const unsigned short* __restrict__ x,
    const unsigned short* __restrict__ w2p,
    const float* __restrict__ b2,
    const float* __restrict__ flow,
    float* __restrict__ out)
{
    __shared__ float lo[16 * 768];
    const int tid = threadIdx.x;
    int bid = blockIdx.x;
    bid = (bid & 7) * 96 + (bid >> 3);               // XCD swizzle
    const int n = bid / HH, h = bid % HH;
    const int wave = tid >> 6, lane = tid & 63;
    const int g = lane >> 4, sl = lane & 15;
    const int s = wave * 16 + sl;

    f32x4 acc[36];
    #pragma unroll
    for (int i = 0; i < 36; ++i) acc[i] = (f32x4)0.0f;

    const unsigned short* xrow = &x[(((size_t)n * HH + h) * WW) * CMID];
    #pragma unroll
    for (int kc = 0; kc < 8; ++kc) {
        short8 bf = *reinterpret_cast<const short8*>(&xrow[s * CMID + kc * 32 + g * 8]);
        const unsigned short* wkc = &w2p[(size_t)kc * 36 * 512];
        #pragma unroll
        for (int tc = 0; tc < 36; ++tc) {
            short8 af = *reinterpret_cast<const short8*>(&wkc[(tc * 64 + lane) * 8]);
            acc[tc] = __builtin_amdgcn_mfma_f32_16x16x32_bf16(af, bf, acc[tc], 0, 0, 0);
        }
    }

    #pragma unroll
    for (int tc = 0; tc < 36; ++tc) {
        const float4 bb = *reinterpret_cast<const float4*>(&b2[tc * 16 + g * 4]);
        acc[tc][0] = 0.25f * (acc[tc][0] + bb.x);
        acc[tc][1] = 0.25f * (acc[tc][1] + bb.y);
        acc[tc][2] = 0.25f * (acc[tc][2] + bb.z);
        acc[tc][3] = 0.25f * (acc[tc][3] + bb.w);
    }

    float pf[2][9];
    #pragma unroll
    for (int ch = 0; ch < 2; ++ch) {
        #pragma unroll
        for (int ki = 0; ki < 3; ++ki) {
            #pragma unroll
            for (int kj = 0; kj < 3; ++kj) {
                int hh2 = h + ki - 1, ww2 = s + kj - 1;
                float v = 0.f;
                if ((unsigned)hh2 < HH && (unsigned)ww2 < WW)
                    v = flow[(((size_t)n * 2 + ch) * HH + hh2) * WW + ww2];
                pf[ch][ki * 3 + kj] = 8.f * v;
            }
        }
    }

    #pragma unroll
    for (int mp = 0; mp < 4; ++mp) {
        #pragma unroll
        for (int i = 0; i < 4; ++i) {
            int pp = mp * 16 + g * 4 + i;
            float L[9];
            #pragma unroll
            for (int k = 0; k < 9; ++k) L[k] = acc[mp + 4 * k][i];
            float mx = L[0];
            #pragma unroll
            for (int k = 1; k < 9; ++k) mx = fmaxf(mx, L[k]);
            float e[9], sum = 0.f;
            #pragma unroll
            for (int k = 0; k < 9; ++k) { e[k] = __expf(L[k] - mx); sum += e[k]; }
            float inv = 1.f / sum;
            int py = pp >> 3, px = pp & 7;
            #pragma unroll
            for (int ch = 0; ch < 2; ++ch) {
                float o = 0.f;
                #pragma unroll
                for (int k = 0; k < 9; ++k) o += e[k] * pf[ch][k];
                lo[(ch * 8 + py) * 768 + s * 8 + px] = o * inv;
            }
        }
    }
    __syncthreads();

    #pragma unroll
    for (int it = 0; it < 8; ++it) {
        int idx = tid + it * 384;
        int row = idx / 192, c4 = idx - row * 192;
        int ch = row >> 3, py = row & 7;
        float4 v = *reinterpret_cast<const float4*>(&lo[row * 768 + c4 * 4]);
        *reinterpret_cast<float4*>(
            &out[(((size_t)n * 2 + ch) * 768 + h * 8 + py) * 768 + c4 * 4]) = v;
    }
}

extern "C" void kernel_launch(void* const* d_in, const int* in_sizes, int n_in,
                              void* d_out, int out_size, void* d_ws, size_t ws_size,
                              hipStream_t stream)
{
    const float* feature = (const float*)d_in[0];
    const float* flow    = (const float*)d_in[1];
    const float* w1      = (const float*)d_in[2];
    const float* b1      = (const float*)d_in[3];
    const float* w2      = (const float*)d_in[4];
    const float* b2      = (const float*)d_in[5];
    float* out = (float*)d_out;

    const size_t featT_bytes = (size_t)NN * HH * WW * CIN * 2;
    const size_t x_bytes     = (size_t)NN * HH * WW * CMID * 2;
    const size_t w1p_bytes   = (size_t)144 * 8192 * 2;
    const size_t w2p_bytes   = (size_t)CO2 * CMID * 2;
    if (ws_size < featT_bytes + x_bytes + w1p_bytes + w2p_bytes) return;

    char* ws = (char*)d_ws;
    unsigned short* featT = (unsigned short*)ws;
    unsigned short* xbuf  = (unsigned short*)(ws + featT_bytes);
    unsigned short* w1p   = (unsigned short*)(ws + featT_bytes + x_bytes);
    unsigned short* w2p   = (unsigned short*)(ws + featT_bytes + x_bytes + w1p_bytes);

    prep_w_kernel<<<4608, 256, 0, stream>>>(w1, w2, w1p, w2p);
    transpose_kernel<<<NN * HH, 256, 0, stream>>>(feature, featT);
    conv1_kernel<<<NN * HH, 256, 0, stream>>>(featT, w1p, b1, xbuf);
    conv2_kernel<<<NN * HH, 384, 0, stream>>>(xbuf, w2p, b2, flow, out);
}

// Round 6
// 501.586 us; speedup vs baseline: 1.2030x; 1.2030x over previous
//
#include <hip/hip_runtime.h>
#include <cstdint>
#include <cstddef>

#define HH 96
#define WW 96
#define NN 8
#define CIN 512
#define CMID 256
#define CO2 576

typedef __attribute__((ext_vector_type(4))) float f32x4;
typedef __attribute__((ext_vector_type(8))) short short8;

static __device__ __forceinline__ unsigned short f2bf(float f) {
    unsigned int u = __float_as_uint(f);
    u += 0x7fffu + ((u >> 16) & 1u);
    return (unsigned short)(u >> 16);
}

static __device__ __forceinline__ void gl_lds16(const void* g, void* l) {
    __builtin_amdgcn_global_load_lds(
        (const __attribute__((address_space(1))) unsigned int*)g,
        (__attribute__((address_space(3))) unsigned int*)l, 16, 0, 0);
}

// w1 (256,512,3,3) OIHW fp32 -> w1p: 144 slabs [(cc,tap)] of 8192 shorts:
//   slab*8192 + co16*512 + lane*8 + e ; co = co16*16+(lane&15),
//   ci = cc*32 + (lane>>4)*8 + e   (wave af load = 1KB contiguous)
// w2 -> w2p [kc(8)][tc(36)][lane(64)][e(8)] ; plus zero out the 2KB zr region.
__global__ __launch_bounds__(256) void prep_w_kernel(
    const float* __restrict__ w1, const float* __restrict__ w2,
    unsigned short* __restrict__ w1p, unsigned short* __restrict__ w2p,
    float* __restrict__ zr)
{
    size_t i = (size_t)blockIdx.x * 256 + threadIdx.x;
    if (blockIdx.x == 0 && threadIdx.x < 128) {
        float4 z; z.x = 0.f; z.y = 0.f; z.z = 0.f; z.w = 0.f;
        reinterpret_cast<float4*>(zr)[threadIdx.x] = z;    // 2048 B of zeros
    }
    if (i < (size_t)144 * 8192) {
        int sb = (int)(i >> 13);
        int r13 = (int)(i & 8191);
        int co16 = r13 >> 9;
        int g = (r13 >> 7) & 3;
        int sl = (r13 >> 3) & 15;
        int e = (int)(i & 7);
        int cc = sb / 9, tap = sb % 9;
        int co = co16 * 16 + sl;
        int ci = cc * 32 + g * 8 + e;
        w1p[i] = f2bf(w1[((size_t)co * CIN + ci) * 9 + tap]);
    }
    if (i < (size_t)8 * 36 * 64 * 8) {
        int idx = (int)i;
        int e = idx & 7;
        int ln = (idx >> 3) & 63;
        int tc = (idx >> 9) % 36;
        int kc = (idx >> 9) / 36;
        int sl = ln & 15, g = ln >> 4;
        int co = tc * 16 + sl;
        int ci = kc * 32 + g * 8 + e;
        w2p[idx] = f2bf(w2[(size_t)co * CMID + ci]);
    }
}

// feature (N,512,96,96) fp32 -> featT [N][H][W][512] bf16
__global__ __launch_bounds__(256) void transpose_kernel(
    const float* __restrict__ f, unsigned short* __restrict__ ft)
{
    __shared__ float t[96 * 65];
    const int tid = threadIdx.x;
    const int b = blockIdx.x;
    const int n = b / HH, h = b % HH;
    for (int cb = 0; cb < 8; ++cb) {
        __syncthreads();
        #pragma unroll
        for (int it = 0; it < 24; ++it) {
            int idx = tid + it * 256;
            int cl = idx / 96, w = idx - cl * 96;
            t[w * 65 + cl] = f[(((size_t)n * CIN + cb * 64 + cl) * HH + h) * WW + w];
        }
        __syncthreads();
        #pragma unroll
        for (int it = 0; it < 24; ++it) {
            int idx = tid + it * 256;
            int w = idx >> 6, cl = idx & 63;
            ft[(((size_t)n * HH + h) * WW + w) * CIN + cb * 64 + cl] = f2bf(t[w * 65 + cl]);
        }
    }
}

// conv1 v6: 3x3, 512->256, bias+ReLU. One block per (n,h), 512 thr = 8 waves,
// wave = 32-co group, tile 96x32 (acc[6][2] = 48 regs -> 4 waves/SIMD).
// B: global_load_lds DMA, linear LDS dest, pre-swizzled per-lane global src
//    (slot c = (r*98+lw)*4 + (s ^ ((lw>>1)&3)); OOB/pad lanes read zr zeros).
//    Double-buffered, ONE barrier per 32-ci chunk.
// A: registers, direct from fragment-ordered w1p, dbuf w/ compile-time parity.
__global__ __launch_bounds__(512, 4) void conv1_kernel(
    const unsigned short* __restrict__ featT,
    const unsigned short* __restrict__ w1p,
    const float* __restrict__ b1,
    const unsigned short* __restrict__ zr,
    unsigned short* __restrict__ x)
{
    __shared__ unsigned short fsB[2][9728];   // 2 x 19456 B (1216 slots x 16B)
    const int tid = threadIdx.x;
    int bid = blockIdx.x;
    bid = (bid & 7) * 96 + (bid >> 3);        // XCD swizzle (768 = 8*96)
    const int n = bid / HH, h = bid % HH;
    const int wave = tid >> 6, lane = tid & 63;
    const int g = lane >> 4, sl = lane & 15;

    f32x4 acc[6][2];
    #pragma unroll
    for (int i = 0; i < 6; ++i) {
        acc[i][0] = (f32x4)0.0f;
        acc[i][1] = (f32x4)0.0f;
    }

    // per-lane DMA source pointers; 19 wave-instructions cover 1216 slots:
    // q = j*8 + wave (j=0,1 all waves; j=2 only waves 0..2)
    const unsigned short* gp[3];
    #pragma unroll
    for (int j = 0; j < 3; ++j) {
        int q = j * 8 + wave;
        int slot = q * 64 + lane;
        int cslot = slot >> 2, sx = slot & 3;
        int rr = cslot / 98, lw = cslot - rr * 98;
        int s = sx ^ ((lw >> 1) & 3);
        int row = h - 1 + rr;
        bool ok = (rr < 3) && (lw >= 1) && (lw <= 96) && ((unsigned)row < HH);
        gp[j] = ok ? &featT[(((size_t)n * HH + row) * WW + (lw - 1)) * CIN + s * 8]
                   : zr;
    }
    const int nq = (wave < 3) ? 3 : 2;

    short8 af0[2], af1[2];

    // prologue: DMA chunk 0 -> buf0; af slab 0 -> af0
    #pragma unroll
    for (int j = 0; j < 3; ++j) {
        if (j < nq) {
            int q = j * 8 + wave;
            gl_lds16(gp[j], &fsB[0][q * 512]);
        }
        gp[j] += 32;
    }
    #pragma unroll
    for (int tc = 0; tc < 2; ++tc)
        af0[tc] = *reinterpret_cast<const short8*>(
            &w1p[(size_t)(((wave * 2 + tc) * 64 + lane) * 8)]);
    __syncthreads();

    auto afload = [&](short8 (&af)[2], int sb1) {
        const unsigned short* ap = &w1p[(size_t)sb1 * 8192];
        #pragma unroll
        for (int tc = 0; tc < 2; ++tc)
            af[tc] = *reinterpret_cast<const short8*>(
                &ap[((wave * 2 + tc) * 64 + lane) * 8]);
    };
    auto compute = [&](short8 (&af)[2], int par, int ki, int kj) {
        #pragma unroll
        for (int ts = 0; ts < 6; ++ts) {
            int lw = ts * 16 + sl + kj;
            int sx = g ^ ((lw >> 1) & 3);
            short8 bf = *reinterpret_cast<const short8*>(
                &fsB[par][((ki * 98 + lw) * 4 + sx) * 8]);
            acc[ts][0] = __builtin_amdgcn_mfma_f32_16x16x32_bf16(
                af[0], bf, acc[ts][0], 0, 0, 0);
            acc[ts][1] = __builtin_amdgcn_mfma_f32_16x16x32_bf16(
                af[1], bf, acc[ts][1], 0, 0, 0);
        }
    };

    for (int ccp = 0; ccp < 8; ++ccp) {
        #pragma unroll
        for (int par = 0; par < 2; ++par) {
            const int cc = ccp * 2 + par;
            // issue next-chunk DMA into the other buffer (drained by barrier)
            if (cc < 15) {
                #pragma unroll
                for (int j = 0; j < 3; ++j) {
                    if (j < nq) {
                        int q = j * 8 + wave;
                        gl_lds16(gp[j], &fsB[par ^ 1][q * 512]);
                    }
                    gp[j] += 32;
                }
            }
            #pragma unroll
            for (int tap = 0; tap < 9; ++tap) {
                const int sbr = cc * 9 + tap;
                const int ki = tap / 3, kj = tap % 3;
                if (((par + tap) & 1) == 0) {
                    if (sbr < 143) afload(af1, sbr + 1);
                    compute(af0, par, ki, kj);
                } else {
                    if (sbr < 143) afload(af0, sbr + 1);
                    compute(af1, par, ki, kj);
                }
            }
            if (cc < 15) __syncthreads();
        }
    }

    // epilogue: bias + ReLU -> bf16 x[n][h][sp][co]
    const size_t rowbase = ((size_t)n * HH + h);
    #pragma unroll
    for (int ts = 0; ts < 6; ++ts) {
        int sp = ts * 16 + sl;
        unsigned short* xp = &x[(rowbase * WW + sp) * CMID];
        #pragma unroll
        for (int tc = 0; tc < 2; ++tc) {
            int co0 = wave * 32 + tc * 16 + g * 4;
            const float4 bb = *reinterpret_cast<const float4*>(&b1[co0]);
            float v0 = acc[ts][tc][0] + bb.x;
            float v1 = acc[ts][tc][1] + bb.y;
            float v2 = acc[ts][tc][2] + bb.z;
            float v3 = acc[ts][tc][3] + bb.w;
            v0 = v0 > 0.f ? v0 : 0.f;
            v1 = v1 > 0.f ? v1 : 0.f;
            v2 = v2 > 0.f ? v2 : 0.f;
            v3 = v3 > 0.f ? v3 : 0.f;
            ushort4 st;
            st.x = f2bf(v0); st.y = f2bf(v1); st.z = f2bf(v2); st.w = f2bf(v3);
            *reinterpret_cast<ushort4*>(&xp[co0]) = st;
        }
    }
}

// conv2 (1x1, 256->576) + bias*0.25 + softmax over 9 taps + flow assembly
__global__ __launch_bounds__(384) void conv2_kernel(
    const unsigned short* __restrict__ x,
    const unsigned short* __restrict__ w2p,
    const float* __restrict__ b2,
    const float* __restrict__ flow,
    float* __restrict__ out)
{
    __shared__ float lo[16 * 768];
    const int tid = threadIdx.x;
    int bid = blockIdx.x;
    bid = (bid & 7) * 96 + (bid >> 3);               // XCD swizzle
    const int n = bid / HH, h = bid % HH;
    const int wave = tid >> 6, lane = tid & 63;
    const int g = lane >> 4, sl = lane & 15;
    const int s = wave * 16 + sl;

    f32x4 acc[36];
    #pragma unroll
    for (int i = 0; i < 36; ++i) acc[i] = (f32x4)0.0f;

    const unsigned short* xrow = &x[(((size_t)n * HH + h) * WW) * CMID];
    #pragma unroll
    for (int kc = 0; kc < 8; ++kc) {
        short8 bf = *reinterpret_cast<const short8*>(&xrow[s * CMID + kc * 32 + g * 8]);
        const unsigned short* wkc = &w2p[(size_t)kc * 36 * 512];
        #pragma unroll
        for (int tc = 0; tc < 36; ++tc) {
            short8 af = *reinterpret_cast<const short8*>(&wkc[(tc * 64 + lane) * 8]);
            acc[tc] = __builtin_amdgcn_mfma_f32_16x16x32_bf16(af, bf, acc[tc], 0, 0, 0);
        }
    }

    #pragma unroll
    for (int tc = 0; tc < 36; ++tc) {
        const float4 bb = *reinterpret_cast<const float4*>(&b2[tc * 16 + g * 4]);
        acc[tc][0] = 0.25f * (acc[tc][0] + bb.x);
        acc[tc][1] = 0.25f * (acc[tc][1] + bb.y);
        acc[tc][2] = 0.25f * (acc[tc][2] + bb.z);
        acc[tc][3] = 0.25f * (acc[tc][3] + bb.w);
    }

    float pf[2][9];
    #pragma unroll
    for (int ch = 0; ch < 2; ++ch) {
        #pragma unroll
        for (int ki = 0; ki < 3; ++ki) {
            #pragma unroll
            for (int kj = 0; kj < 3; ++kj) {
                int hh2 = h + ki - 1, ww2 = s + kj - 1;
                float v = 0.f;
                if ((unsigned)hh2 < HH && (unsigned)ww2 < WW)
                    v = flow[(((size_t)n * 2 + ch) * HH + hh2) * WW + ww2];
                pf[ch][ki * 3 + kj] = 8.f * v;
            }
        }
    }

    #pragma unroll
    for (int mp = 0; mp < 4; ++mp) {
        #pragma unroll
        for (int i = 0; i < 4; ++i) {
            int pp = mp * 16 + g * 4 + i;
            float L[9];
            #pragma unroll
            for (int k = 0; k < 9; ++k) L[k] = acc[mp + 4 * k][i];
            float mx = L[0];
            #pragma unroll
            for (int k = 1; k < 9; ++k) mx = fmaxf(mx, L[k]);
            float e[9], sum = 0.f;
            #pragma unroll
            for (int k = 0; k < 9; ++k) { e[k] = __expf(L[k] - mx); sum += e[k]; }
            float inv = 1.f / sum;
            int py = pp >> 3, px = pp & 7;
            #pragma unroll
            for (int ch = 0; ch < 2; ++ch) {
                float o = 0.f;
                #pragma unroll
                for (int k = 0; k < 9; ++k) o += e[k] * pf[ch][k];
                lo[(ch * 8 + py) * 768 + s * 8 + px] = o * inv;
            }
        }
    }
    __syncthreads();

    #pragma unroll
    for (int it = 0; it < 8; ++it) {
        int idx = tid + it * 384;
        int row = idx / 192, c4 = idx - row * 192;
        int ch = row >> 3, py = row & 7;
        float4 v = *reinterpret_cast<const float4*>(&lo[row * 768 + c4 * 4]);
        *reinterpret_cast<float4*>(
            &out[(((size_t)n * 2 + ch) * 768 + h * 8 + py) * 768 + c4 * 4]) = v;
    }
}

extern "C" void kernel_launch(void* const* d_in, const int* in_sizes, int n_in,
                              void* d_out, int out_size, void* d_ws, size_t ws_size,
                              hipStream_t stream)
{
    const float* feature = (const float*)d_in[0];
    const float* flow    = (const float*)d_in[1];
    const float* w1      = (const float*)d_in[2];
    const float* b1      = (const float*)d_in[3];
    const float* w2      = (const float*)d_in[4];
    const float* b2      = (const float*)d_in[5];
    float* out = (float*)d_out;

    const size_t featT_bytes = (size_t)NN * HH * WW * CIN * 2;
    const size_t x_bytes     = (size_t)NN * HH * WW * CMID * 2;
    const size_t w1p_bytes   = (size_t)144 * 8192 * 2;
    const size_t w2p_bytes   = (size_t)CO2 * CMID * 2;
    const size_t zr_bytes    = 2048;
    if (ws_size < featT_bytes + x_bytes + w1p_bytes + w2p_bytes + zr_bytes) return;

    char* ws = (char*)d_ws;
    unsigned short* featT = (unsigned short*)ws;
    unsigned short* xbuf  = (unsigned short*)(ws + featT_bytes);
    unsigned short* w1p   = (unsigned short*)(ws + featT_bytes + x_bytes);
    unsigned short* w2p   = (unsigned short*)(ws + featT_bytes + x_bytes + w1p_bytes);
    unsigned short* zr    = (unsigned short*)(ws + featT_bytes + x_bytes + w1p_bytes + w2p_bytes);

    prep_w_kernel<<<4608, 256, 0, stream>>>(w1, w2, w1p, w2p, (float*)zr);
    transpose_kernel<<<NN * HH, 256, 0, stream>>>(feature, featT);
    conv1_kernel<<<NN * HH, 512, 0, stream>>>(featT, w1p, b1, zr, xbuf);
    conv2_kernel<<<NN * HH, 384, 0, stream>>>(xbuf, w2p, b2, flow, out);
}

// Round 7
// 417.453 us; speedup vs baseline: 1.4455x; 1.2015x over previous
//
#include <hip/hip_runtime.h>
#include <cstdint>
#include <cstddef>

#define HH 96
#define WW 96
#define NN 8
#define CIN 512
#define CMID 256
#define CO2 576

typedef __attribute__((ext_vector_type(4))) float f32x4;
typedef __attribute__((ext_vector_type(8))) short short8;

static __device__ __forceinline__ unsigned short f2bf(float f) {
    unsigned int u = __float_as_uint(f);
    u += 0x7fffu + ((u >> 16) & 1u);
    return (unsigned short)(u >> 16);
}

static __device__ __forceinline__ void gl_lds16(const void* g, void* l) {
    __builtin_amdgcn_global_load_lds(
        (const __attribute__((address_space(1))) unsigned int*)g,
        (__attribute__((address_space(3))) unsigned int*)l, 16, 0, 0);
}

// w1 (256,512,3,3) OIHW fp32 -> w1p: 144 slabs [(cc,tap)] of 8192 shorts:
//   slab*8192 + co16*512 + lane*8 + e ; co = co16*16+(lane&15),
//   ci = cc*32 + (lane>>4)*8 + e   (wave af load = 1KB contiguous)
// w2 -> w2p [kc(8)][tc(36)][lane(64)][e(8)] ; plus zero out the 2KB zr region.
__global__ __launch_bounds__(256) void prep_w_kernel(
    const float* __restrict__ w1, const float* __restrict__ w2,
    unsigned short* __restrict__ w1p, unsigned short* __restrict__ w2p,
    float* __restrict__ zr)
{
    size_t i = (size_t)blockIdx.x * 256 + threadIdx.x;
    if (blockIdx.x == 0 && threadIdx.x < 128) {
        float4 z; z.x = 0.f; z.y = 0.f; z.z = 0.f; z.w = 0.f;
        reinterpret_cast<float4*>(zr)[threadIdx.x] = z;    // 2048 B of zeros
    }
    if (i < (size_t)144 * 8192) {
        int sb = (int)(i >> 13);
        int r13 = (int)(i & 8191);
        int co16 = r13 >> 9;
        int g = (r13 >> 7) & 3;
        int sl = (r13 >> 3) & 15;
        int e = (int)(i & 7);
        int cc = sb / 9, tap = sb % 9;
        int co = co16 * 16 + sl;
        int ci = cc * 32 + g * 8 + e;
        w1p[i] = f2bf(w1[((size_t)co * CIN + ci) * 9 + tap]);
    }
    if (i < (size_t)8 * 36 * 64 * 8) {
        int idx = (int)i;
        int e = idx & 7;
        int ln = (idx >> 3) & 63;
        int tc = (idx >> 9) % 36;
        int kc = (idx >> 9) / 36;
        int sl = ln & 15, g = ln >> 4;
        int co = tc * 16 + sl;
        int ci = kc * 32 + g * 8 + e;
        w2p[idx] = f2bf(w2[(size_t)co * CMID + ci]);
    }
}

// feature (N,512,96,96) fp32 -> featT [N][H][W][512] bf16
__global__ __launch_bounds__(256) void transpose_kernel(
    const float* __restrict__ f, unsigned short* __restrict__ ft)
{
    __shared__ float t[96 * 65];
    const int tid = threadIdx.x;
    const int b = blockIdx.x;
    const int n = b / HH, h = b % HH;
    for (int cb = 0; cb < 8; ++cb) {
        __syncthreads();
        #pragma unroll
        for (int it = 0; it < 24; ++it) {
            int idx = tid + it * 256;
            int cl = idx / 96, w = idx - cl * 96;
            t[w * 65 + cl] = f[(((size_t)n * CIN + cb * 64 + cl) * HH + h) * WW + w];
        }
        __syncthreads();
        #pragma unroll
        for (int it = 0; it < 24; ++it) {
            int idx = tid + it * 256;
            int w = idx >> 6, cl = idx & 63;
            ft[(((size_t)n * HH + h) * WW + w) * CIN + cb * 64 + cl] = f2bf(t[w * 65 + cl]);
        }
    }
}

// conv1 v6: 3x3, 512->256, bias+ReLU. One block per (n,h), 512 thr = 8 waves,
// wave = 32-co group, tile 96x32 (acc[6][2] = 48 regs -> 4 waves/SIMD).
// B: global_load_lds DMA, linear LDS dest, pre-swizzled per-lane global src.
// A: registers, direct from fragment-ordered w1p, dbuf w/ compile-time parity.
__global__ __launch_bounds__(512, 4) void conv1_kernel(
    const unsigned short* __restrict__ featT,
    const unsigned short* __restrict__ w1p,
    const float* __restrict__ b1,
    const unsigned short* __restrict__ zr,
    unsigned short* __restrict__ x)
{
    __shared__ unsigned short fsB[2][9728];   // 2 x 19456 B (1216 slots x 16B)
    const int tid = threadIdx.x;
    int bid = blockIdx.x;
    bid = (bid & 7) * 96 + (bid >> 3);        // XCD swizzle (768 = 8*96)
    const int n = bid / HH, h = bid % HH;
    const int wave = tid >> 6, lane = tid & 63;
    const int g = lane >> 4, sl = lane & 15;

    f32x4 acc[6][2];
    #pragma unroll
    for (int i = 0; i < 6; ++i) {
        acc[i][0] = (f32x4)0.0f;
        acc[i][1] = (f32x4)0.0f;
    }

    const unsigned short* gp[3];
    #pragma unroll
    for (int j = 0; j < 3; ++j) {
        int q = j * 8 + wave;
        int slot = q * 64 + lane;
        int cslot = slot >> 2, sx = slot & 3;
        int rr = cslot / 98, lw = cslot - rr * 98;
        int s = sx ^ ((lw >> 1) & 3);
        int row = h - 1 + rr;
        bool ok = (rr < 3) && (lw >= 1) && (lw <= 96) && ((unsigned)row < HH);
        gp[j] = ok ? &featT[(((size_t)n * HH + row) * WW + (lw - 1)) * CIN + s * 8]
                   : zr;
    }
    const int nq = (wave < 3) ? 3 : 2;

    short8 af0[2], af1[2];

    #pragma unroll
    for (int j = 0; j < 3; ++j) {
        if (j < nq) {
            int q = j * 8 + wave;
            gl_lds16(gp[j], &fsB[0][q * 512]);
        }
        gp[j] += 32;
    }
    #pragma unroll
    for (int tc = 0; tc < 2; ++tc)
        af0[tc] = *reinterpret_cast<const short8*>(
            &w1p[(size_t)(((wave * 2 + tc) * 64 + lane) * 8)]);
    __syncthreads();

    auto afload = [&](short8 (&af)[2], int sb1) {
        const unsigned short* ap = &w1p[(size_t)sb1 * 8192];
        #pragma unroll
        for (int tc = 0; tc < 2; ++tc)
            af[tc] = *reinterpret_cast<const short8*>(
                &ap[((wave * 2 + tc) * 64 + lane) * 8]);
    };
    auto compute = [&](short8 (&af)[2], int par, int ki, int kj) {
        #pragma unroll
        for (int ts = 0; ts < 6; ++ts) {
            int lw = ts * 16 + sl + kj;
            int sx = g ^ ((lw >> 1) & 3);
            short8 bf = *reinterpret_cast<const short8*>(
                &fsB[par][((ki * 98 + lw) * 4 + sx) * 8]);
            acc[ts][0] = __builtin_amdgcn_mfma_f32_16x16x32_bf16(
                af[0], bf, acc[ts][0], 0, 0, 0);
            acc[ts][1] = __builtin_amdgcn_mfma_f32_16x16x32_bf16(
                af[1], bf, acc[ts][1], 0, 0, 0);
        }
    };

    for (int ccp = 0; ccp < 8; ++ccp) {
        #pragma unroll
        for (int par = 0; par < 2; ++par) {
            const int cc = ccp * 2 + par;
            if (cc < 15) {
                #pragma unroll
                for (int j = 0; j < 3; ++j) {
                    if (j < nq) {
                        int q = j * 8 + wave;
                        gl_lds16(gp[j], &fsB[par ^ 1][q * 512]);
                    }
                    gp[j] += 32;
                }
            }
            #pragma unroll
            for (int tap = 0; tap < 9; ++tap) {
                const int sbr = cc * 9 + tap;
                const int ki = tap / 3, kj = tap % 3;
                if (((par + tap) & 1) == 0) {
                    if (sbr < 143) afload(af1, sbr + 1);
                    compute(af0, par, ki, kj);
                } else {
                    if (sbr < 143) afload(af0, sbr + 1);
                    compute(af1, par, ki, kj);
                }
            }
            if (cc < 15) __syncthreads();
        }
    }

    const size_t rowbase = ((size_t)n * HH + h);
    #pragma unroll
    for (int ts = 0; ts < 6; ++ts) {
        int sp = ts * 16 + sl;
        unsigned short* xp = &x[(rowbase * WW + sp) * CMID];
        #pragma unroll
        for (int tc = 0; tc < 2; ++tc) {
            int co0 = wave * 32 + tc * 16 + g * 4;
            const float4 bb = *reinterpret_cast<const float4*>(&b1[co0]);
            float v0 = acc[ts][tc][0] + bb.x;
            float v1 = acc[ts][tc][1] + bb.y;
            float v2 = acc[ts][tc][2] + bb.z;
            float v3 = acc[ts][tc][3] + bb.w;
            v0 = v0 > 0.f ? v0 : 0.f;
            v1 = v1 > 0.f ? v1 : 0.f;
            v2 = v2 > 0.f ? v2 : 0.f;
            v3 = v3 > 0.f ? v3 : 0.f;
            ushort4 st;
            st.x = f2bf(v0); st.y = f2bf(v1); st.z = f2bf(v2); st.w = f2bf(v3);
            *reinterpret_cast<ushort4*>(&xp[co0]) = st;
        }
    }
}

// conv2 v7 (1x1, 256->576) + bias*0.25 + softmax + flow assembly.
// Block = 48 pixels (half row), grid 1536. 6 waves = 3 pixel-groups x 2
// pp-halves; wave tiles tc = 4k + 2*ph + q -> acc[9][2] = 72 VGPRs.
// Softmax over k stays lane-local: pp = 32*ph + 16*q + 4*g + i fixed per (q,i).
__global__ __launch_bounds__(384, 3) void conv2_kernel(
    const unsigned short* __restrict__ x,
    const unsigned short* __restrict__ w2p,
    const float* __restrict__ b2,
    const float* __restrict__ flow,
    float* __restrict__ out)
{
    __shared__ float lo[16 * 384];
    const int tid = threadIdx.x;
    int bid = blockIdx.x;
    bid = (bid & 7) * 192 + (bid >> 3);          // XCD swizzle (1536 = 8*192)
    const int n = bid / (HH * 2);
    const int rem = bid % (HH * 2);
    const int h = rem >> 1, wh = rem & 1;
    const int wave = tid >> 6, lane = tid & 63;
    const int g = lane >> 4, sl = lane & 15;
    const int pg = wave >> 1, ph = wave & 1;
    const int s_abs = wh * 48 + pg * 16 + sl;    // pixel this lane owns
    const int s_loc = pg * 16 + sl;

    f32x4 acc[9][2];
    #pragma unroll
    for (int k = 0; k < 9; ++k) {
        acc[k][0] = (f32x4)0.0f;
        acc[k][1] = (f32x4)0.0f;
    }

    const unsigned short* xp = &x[(((size_t)n * HH + h) * WW + s_abs) * CMID];
    #pragma unroll
    for (int kc = 0; kc < 8; ++kc) {
        short8 bf = *reinterpret_cast<const short8*>(&xp[kc * 32 + g * 8]);
        const unsigned short* wkc = &w2p[(size_t)kc * 36 * 512];
        #pragma unroll
        for (int k = 0; k < 9; ++k) {
            #pragma unroll
            for (int q = 0; q < 2; ++q) {
                int tc = 4 * k + 2 * ph + q;
                short8 af = *reinterpret_cast<const short8*>(
                    &wkc[(tc * 64 + lane) * 8]);
                acc[k][q] = __builtin_amdgcn_mfma_f32_16x16x32_bf16(
                    af, bf, acc[k][q], 0, 0, 0);
            }
        }
    }

    // bias + 0.25 scale
    #pragma unroll
    for (int k = 0; k < 9; ++k) {
        #pragma unroll
        for (int q = 0; q < 2; ++q) {
            int co0 = (4 * k + 2 * ph + q) * 16 + g * 4;
            const float4 bb = *reinterpret_cast<const float4*>(&b2[co0]);
            acc[k][q][0] = 0.25f * (acc[k][q][0] + bb.x);
            acc[k][q][1] = 0.25f * (acc[k][q][1] + bb.y);
            acc[k][q][2] = 0.25f * (acc[k][q][2] + bb.z);
            acc[k][q][3] = 0.25f * (acc[k][q][3] + bb.w);
        }
    }

    // 8*flow 3x3 neighborhood (zero-padded) for this lane's pixel
    float pf[2][9];
    #pragma unroll
    for (int ch = 0; ch < 2; ++ch) {
        #pragma unroll
        for (int ki = 0; ki < 3; ++ki) {
            #pragma unroll
            for (int kj = 0; kj < 3; ++kj) {
                int hh2 = h + ki - 1, ww2 = s_abs + kj - 1;
                float v = 0.f;
                if ((unsigned)hh2 < HH && (unsigned)ww2 < WW)
                    v = flow[(((size_t)n * 2 + ch) * HH + hh2) * WW + ww2];
                pf[ch][ki * 3 + kj] = 8.f * v;
            }
        }
    }

    // lane-local softmax over the 9 taps, 8 pp values per lane
    #pragma unroll
    for (int q = 0; q < 2; ++q) {
        #pragma unroll
        for (int i = 0; i < 4; ++i) {
            int pp = 32 * ph + 16 * q + 4 * g + i;
            float L[9];
            #pragma unroll
            for (int k = 0; k < 9; ++k) L[k] = acc[k][q][i];
            float mx = L[0];
            #pragma unroll
            for (int k = 1; k < 9; ++k) mx = fmaxf(mx, L[k]);
            float e[9], sum = 0.f;
            #pragma unroll
            for (int k = 0; k < 9; ++k) { e[k] = __expf(L[k] - mx); sum += e[k]; }
            float inv = 1.f / sum;
            int py = pp >> 3, px = pp & 7;
            #pragma unroll
            for (int ch = 0; ch < 2; ++ch) {
                float o = 0.f;
                #pragma unroll
                for (int k = 0; k < 9; ++k) o += e[k] * pf[ch][k];
                lo[(ch * 8 + py) * 384 + s_loc * 8 + px] = o * inv;
            }
        }
    }
    __syncthreads();

    // coalesced output: 16 rows of 384 floats (this block's half row)
    #pragma unroll
    for (int it = 0; it < 4; ++it) {
        int idx = tid + it * 384;                 // float4 index, 0..1535
        int row = idx / 96, c4 = idx - row * 96;
        int ch = row >> 3, py = row & 7;
        float4 v = *reinterpret_cast<const float4*>(&lo[row * 384 + c4 * 4]);
        *reinterpret_cast<float4*>(
            &out[(((size_t)n * 2 + ch) * 768 + h * 8 + py) * 768 +
                 wh * 384 + c4 * 4]) = v;
    }
}

extern "C" void kernel_launch(void* const* d_in, const int* in_sizes, int n_in,
                              void* d_out, int out_size, void* d_ws, size_t ws_size,
                              hipStream_t stream)
{
    const float* feature = (const float*)d_in[0];
    const float* flow    = (const float*)d_in[1];
    const float* w1      = (const float*)d_in[2];
    const float* b1      = (const float*)d_in[3];
    const float* w2      = (const float*)d_in[4];
    const float* b2      = (const float*)d_in[5];
    float* out = (float*)d_out;

    const size_t featT_bytes = (size_t)NN * HH * WW * CIN * 2;
    const size_t x_bytes     = (size_t)NN * HH * WW * CMID * 2;
    const size_t w1p_bytes   = (size_t)144 * 8192 * 2;
    const size_t w2p_bytes   = (size_t)CO2 * CMID * 2;
    const size_t zr_bytes    = 2048;
    if (ws_size < featT_bytes + x_bytes + w1p_bytes + w2p_bytes + zr_bytes) return;

    char* ws = (char*)d_ws;
    unsigned short* featT = (unsigned short*)ws;
    unsigned short* xbuf  = (unsigned short*)(ws + featT_bytes);
    unsigned short* w1p   = (unsigned short*)(ws + featT_bytes + x_bytes);
    unsigned short* w2p   = (unsigned short*)(ws + featT_bytes + x_bytes + w1p_bytes);
    unsigned short* zr    = (unsigned short*)(ws + featT_bytes + x_bytes + w1p_bytes + w2p_bytes);

    prep_w_kernel<<<4608, 256, 0, stream>>>(w1, w2, w1p, w2p, (float*)zr);
    transpose_kernel<<<NN * HH, 256, 0, stream>>>(feature, featT);
    conv1_kernel<<<NN * HH, 512, 0, stream>>>(featT, w1p, b1, zr, xbuf);
    conv2_kernel<<<NN * HH * 2, 384, 0, stream>>>(xbuf, w2p, b2, flow, out);
}

// Round 8
// 352.152 us; speedup vs baseline: 1.7136x; 1.1854x over previous
//
#include <hip/hip_runtime.h>
#include <cstdint>
#include <cstddef>

#define HH 96
#define WW 96
#define NN 8
#define CIN 512
#define CMID 256
#define CO2 576

typedef __attribute__((ext_vector_type(4))) float f32x4;
typedef __attribute__((ext_vector_type(8))) short short8;

static __device__ __forceinline__ unsigned short f2bf(float f) {
    unsigned int u = __float_as_uint(f);
    u += 0x7fffu + ((u >> 16) & 1u);
    return (unsigned short)(u >> 16);
}

static __device__ __forceinline__ void gl_lds16(const void* g, void* l) {
    __builtin_amdgcn_global_load_lds(
        (const __attribute__((address_space(1))) unsigned int*)g,
        (__attribute__((address_space(3))) unsigned int*)l, 16, 0, 0);
}

// w1 (256,512,3,3) OIHW fp32 -> w1p: 144 slabs [(cc,tap)] of 8192 shorts:
//   slab*8192 + co16*512 + lane*8 + e ; co = co16*16+(lane&15),
//   ci = cc*32 + (lane>>4)*8 + e   (wave af load = 1KB contiguous)
// w2 -> w2p [kc(8)][tc(36)][lane(64)][e(8)] ; plus zero out the 2KB zr region.
__global__ __launch_bounds__(256) void prep_w_kernel(
    const float* __restrict__ w1, const float* __restrict__ w2,
    unsigned short* __restrict__ w1p, unsigned short* __restrict__ w2p,
    float* __restrict__ zr)
{
    size_t i = (size_t)blockIdx.x * 256 + threadIdx.x;
    if (blockIdx.x == 0 && threadIdx.x < 128) {
        float4 z; z.x = 0.f; z.y = 0.f; z.z = 0.f; z.w = 0.f;
        reinterpret_cast<float4*>(zr)[threadIdx.x] = z;    // 2048 B of zeros
    }
    if (i < (size_t)144 * 8192) {
        int sb = (int)(i >> 13);
        int r13 = (int)(i & 8191);
        int co16 = r13 >> 9;
        int g = (r13 >> 7) & 3;
        int sl = (r13 >> 3) & 15;
        int e = (int)(i & 7);
        int cc = sb / 9, tap = sb % 9;
        int co = co16 * 16 + sl;
        int ci = cc * 32 + g * 8 + e;
        w1p[i] = f2bf(w1[((size_t)co * CIN + ci) * 9 + tap]);
    }
    if (i < (size_t)8 * 36 * 64 * 8) {
        int idx = (int)i;
        int e = idx & 7;
        int ln = (idx >> 3) & 63;
        int tc = (idx >> 9) % 36;
        int kc = (idx >> 9) / 36;
        int sl = ln & 15, g = ln >> 4;
        int co = tc * 16 + sl;
        int ci = kc * 32 + g * 8 + e;
        w2p[idx] = f2bf(w2[(size_t)co * CMID + ci]);
    }
}

// feature (N,512,96,96) fp32 -> featT [N][H][W][512] bf16
__global__ __launch_bounds__(256) void transpose_kernel(
    const float* __restrict__ f, unsigned short* __restrict__ ft)
{
    __shared__ float t[96 * 65];
    const int tid = threadIdx.x;
    const int b = blockIdx.x;
    const int n = b / HH, h = b % HH;
    for (int cb = 0; cb < 8; ++cb) {
        __syncthreads();
        #pragma unroll
        for (int it = 0; it < 24; ++it) {
            int idx = tid + it * 256;
            int cl = idx / 96, w = idx - cl * 96;
            t[w * 65 + cl] = f[(((size_t)n * CIN + cb * 64 + cl) * HH + h) * WW + w];
        }
        __syncthreads();
        #pragma unroll
        for (int it = 0; it < 24; ++it) {
            int idx = tid + it * 256;
            int w = idx >> 6, cl = idx & 63;
            ft[(((size_t)n * HH + h) * WW + w) * CIN + cb * 64 + cl] = f2bf(t[w * 65 + cl]);
        }
    }
}

// conv1 v6: 3x3, 512->256, bias+ReLU. One block per (n,h), 512 thr = 8 waves,
// wave = 32-co group, tile 96x32 (acc[6][2] = 48 regs -> 4 waves/SIMD).
// B: global_load_lds DMA, linear LDS dest, pre-swizzled per-lane global src.
// A: registers, direct from fragment-ordered w1p, dbuf w/ compile-time parity.
__global__ __launch_bounds__(512, 4) void conv1_kernel(
    const unsigned short* __restrict__ featT,
    const unsigned short* __restrict__ w1p,
    const float* __restrict__ b1,
    const unsigned short* __restrict__ zr,
    unsigned short* __restrict__ x)
{
    __shared__ unsigned short fsB[2][9728];   // 2 x 19456 B (1216 slots x 16B)
    const int tid = threadIdx.x;
    int bid = blockIdx.x;
    bid = (bid & 7) * 96 + (bid >> 3);        // XCD swizzle (768 = 8*96)
    const int n = bid / HH, h = bid % HH;
    const int wave = tid >> 6, lane = tid & 63;
    const int g = lane >> 4, sl = lane & 15;

    f32x4 acc[6][2];
    #pragma unroll
    for (int i = 0; i < 6; ++i) {
        acc[i][0] = (f32x4)0.0f;
        acc[i][1] = (f32x4)0.0f;
    }

    const unsigned short* gp[3];
    #pragma unroll
    for (int j = 0; j < 3; ++j) {
        int q = j * 8 + wave;
        int slot = q * 64 + lane;
        int cslot = slot >> 2, sx = slot & 3;
        int rr = cslot / 98, lw = cslot - rr * 98;
        int s = sx ^ ((lw >> 1) & 3);
        int row = h - 1 + rr;
        bool ok = (rr < 3) && (lw >= 1) && (lw <= 96) && ((unsigned)row < HH);
        gp[j] = ok ? &featT[(((size_t)n * HH + row) * WW + (lw - 1)) * CIN + s * 8]
                   : zr;
    }
    const int nq = (wave < 3) ? 3 : 2;

    short8 af0[2], af1[2];

    #pragma unroll
    for (int j = 0; j < 3; ++j) {
        if (j < nq) {
            int q = j * 8 + wave;
            gl_lds16(gp[j], &fsB[0][q * 512]);
        }
        gp[j] += 32;
    }
    #pragma unroll
    for (int tc = 0; tc < 2; ++tc)
        af0[tc] = *reinterpret_cast<const short8*>(
            &w1p[(size_t)(((wave * 2 + tc) * 64 + lane) * 8)]);
    __syncthreads();

    auto afload = [&](short8 (&af)[2], int sb1) {
        const unsigned short* ap = &w1p[(size_t)sb1 * 8192];
        #pragma unroll
        for (int tc = 0; tc < 2; ++tc)
            af[tc] = *reinterpret_cast<const short8*>(
                &ap[((wave * 2 + tc) * 64 + lane) * 8]);
    };
    auto compute = [&](short8 (&af)[2], int par, int ki, int kj) {
        #pragma unroll
        for (int ts = 0; ts < 6; ++ts) {
            int lw = ts * 16 + sl + kj;
            int sx = g ^ ((lw >> 1) & 3);
            short8 bf = *reinterpret_cast<const short8*>(
                &fsB[par][((ki * 98 + lw) * 4 + sx) * 8]);
            acc[ts][0] = __builtin_amdgcn_mfma_f32_16x16x32_bf16(
                af[0], bf, acc[ts][0], 0, 0, 0);
            acc[ts][1] = __builtin_amdgcn_mfma_f32_16x16x32_bf16(
                af[1], bf, acc[ts][1], 0, 0, 0);
        }
    };

    for (int ccp = 0; ccp < 8; ++ccp) {
        #pragma unroll
        for (int par = 0; par < 2; ++par) {
            const int cc = ccp * 2 + par;
            if (cc < 15) {
                #pragma unroll
                for (int j = 0; j < 3; ++j) {
                    if (j < nq) {
                        int q = j * 8 + wave;
                        gl_lds16(gp[j], &fsB[par ^ 1][q * 512]);
                    }
                    gp[j] += 32;
                }
            }
            #pragma unroll
            for (int tap = 0; tap < 9; ++tap) {
                const int sbr = cc * 9 + tap;
                const int ki = tap / 3, kj = tap % 3;
                if (((par + tap) & 1) == 0) {
                    if (sbr < 143) afload(af1, sbr + 1);
                    compute(af0, par, ki, kj);
                } else {
                    if (sbr < 143) afload(af0, sbr + 1);
                    compute(af1, par, ki, kj);
                }
            }
            if (cc < 15) __syncthreads();
        }
    }

    const size_t rowbase = ((size_t)n * HH + h);
    #pragma unroll
    for (int ts = 0; ts < 6; ++ts) {
        int sp = ts * 16 + sl;
        unsigned short* xp = &x[(rowbase * WW + sp) * CMID];
        #pragma unroll
        for (int tc = 0; tc < 2; ++tc) {
            int co0 = wave * 32 + tc * 16 + g * 4;
            const float4 bb = *reinterpret_cast<const float4*>(&b1[co0]);
            float v0 = acc[ts][tc][0] + bb.x;
            float v1 = acc[ts][tc][1] + bb.y;
            float v2 = acc[ts][tc][2] + bb.z;
            float v3 = acc[ts][tc][3] + bb.w;
            v0 = v0 > 0.f ? v0 : 0.f;
            v1 = v1 > 0.f ? v1 : 0.f;
            v2 = v2 > 0.f ? v2 : 0.f;
            v3 = v3 > 0.f ? v3 : 0.f;
            ushort4 st;
            st.x = f2bf(v0); st.y = f2bf(v1); st.z = f2bf(v2); st.w = f2bf(v3);
            *reinterpret_cast<ushort4*>(&xp[co0]) = st;
        }
    }
}

// conv2 v8 (1x1, 256->576) + bias*0.25 + softmax + flow assembly.
// Block = 32 pixels, 512 thr = 8 waves = 2 pixel-groups x 4 pp-quarters.
// Wave q owns tiles tc = 4k+q (k=0..8): acc[9] = 36 VGPRs, softmax lane-local
// (channel = 64k + pp, pp = 16q + 4g + i fixed per i). Grid 2304 = 8*288.
__global__ __launch_bounds__(512, 4) void conv2_kernel(
    const unsigned short* __restrict__ x,
    const unsigned short* __restrict__ w2p,
    const float* __restrict__ b2,
    const float* __restrict__ flow,
    float* __restrict__ out)
{
    __shared__ float lo[16 * 256];               // 16 KB
    const int tid = threadIdx.x;
    int bid = blockIdx.x;
    bid = (bid & 7) * 288 + (bid >> 3);          // XCD swizzle (2304 = 8*288)
    const int n = bid / 288;
    const int rem = bid % 288;
    const int h = rem / 3, third = rem % 3;
    const int wave = tid >> 6, lane = tid & 63;
    const int g = lane >> 4, sl = lane & 15;
    const int q = wave & 3, pxg = wave >> 2;
    const int s_abs = third * 32 + pxg * 16 + sl;   // pixel this lane owns
    const int s_loc = pxg * 16 + sl;                // 0..31

    f32x4 acc[9];
    #pragma unroll
    for (int k = 0; k < 9; ++k) acc[k] = (f32x4)0.0f;

    const unsigned short* xp = &x[(((size_t)n * HH + h) * WW + s_abs) * CMID];
    #pragma unroll
    for (int kc = 0; kc < 8; ++kc) {
        short8 bf = *reinterpret_cast<const short8*>(&xp[kc * 32 + g * 8]);
        const unsigned short* wkc = &w2p[(size_t)kc * 36 * 512];
        #pragma unroll
        for (int k = 0; k < 9; ++k) {
            int tc = 4 * k + q;
            short8 af = *reinterpret_cast<const short8*>(&wkc[(tc * 64 + lane) * 8]);
            acc[k] = __builtin_amdgcn_mfma_f32_16x16x32_bf16(af, bf, acc[k], 0, 0, 0);
        }
    }

    // bias + 0.25 scale
    #pragma unroll
    for (int k = 0; k < 9; ++k) {
        int co0 = (4 * k + q) * 16 + g * 4;
        const float4 bb = *reinterpret_cast<const float4*>(&b2[co0]);
        acc[k][0] = 0.25f * (acc[k][0] + bb.x);
        acc[k][1] = 0.25f * (acc[k][1] + bb.y);
        acc[k][2] = 0.25f * (acc[k][2] + bb.z);
        acc[k][3] = 0.25f * (acc[k][3] + bb.w);
    }

    // 8*flow 3x3 neighborhood (zero-padded) for this lane's pixel
    float pf[2][9];
    #pragma unroll
    for (int ch = 0; ch < 2; ++ch) {
        #pragma unroll
        for (int ki = 0; ki < 3; ++ki) {
            #pragma unroll
            for (int kj = 0; kj < 3; ++kj) {
                int hh2 = h + ki - 1, ww2 = s_abs + kj - 1;
                float v = 0.f;
                if ((unsigned)hh2 < HH && (unsigned)ww2 < WW)
                    v = flow[(((size_t)n * 2 + ch) * HH + hh2) * WW + ww2];
                pf[ch][ki * 3 + kj] = 8.f * v;
            }
        }
    }

    // lane-local softmax over the 9 taps; 4 pp values per lane
    #pragma unroll
    for (int i = 0; i < 4; ++i) {
        int pp = 16 * q + 4 * g + i;
        float L[9];
        #pragma unroll
        for (int k = 0; k < 9; ++k) L[k] = acc[k][i];
        float mx = L[0];
        #pragma unroll
        for (int k = 1; k < 9; ++k) mx = fmaxf(mx, L[k]);
        float e[9], sum = 0.f;
        #pragma unroll
        for (int k = 0; k < 9; ++k) { e[k] = __expf(L[k] - mx); sum += e[k]; }
        float inv = 1.f / sum;
        int py = pp >> 3, px = pp & 7;
        #pragma unroll
        for (int ch = 0; ch < 2; ++ch) {
            float o = 0.f;
            #pragma unroll
            for (int k = 0; k < 9; ++k) o += e[k] * pf[ch][k];
            lo[(ch * 8 + py) * 256 + s_loc * 8 + px] = o * inv;
        }
    }
    __syncthreads();

    // coalesced output: 16 rows x 256 floats (this block's 32-pixel span)
    #pragma unroll
    for (int it = 0; it < 2; ++it) {
        int idx = tid + it * 512;                 // float4 index, 0..1023
        int row = idx >> 6, c4 = idx & 63;
        int ch = row >> 3, py = row & 7;
        float4 v = *reinterpret_cast<const float4*>(&lo[row * 256 + c4 * 4]);
        *reinterpret_cast<float4*>(
            &out[(((size_t)n * 2 + ch) * 768 + h * 8 + py) * 768 +
                 third * 256 + c4 * 4]) = v;
    }
}

extern "C" void kernel_launch(void* const* d_in, const int* in_sizes, int n_in,
                              void* d_out, int out_size, void* d_ws, size_t ws_size,
                              hipStream_t stream)
{
    const float* feature = (const float*)d_in[0];
    const float* flow    = (const float*)d_in[1];
    const float* w1      = (const float*)d_in[2];
    const float* b1      = (const float*)d_in[3];
    const float* w2      = (const float*)d_in[4];
    const float* b2      = (const float*)d_in[5];
    float* out = (float*)d_out;

    const size_t featT_bytes = (size_t)NN * HH * WW * CIN * 2;
    const size_t x_bytes     = (size_t)NN * HH * WW * CMID * 2;
    const size_t w1p_bytes   = (size_t)144 * 8192 * 2;
    const size_t w2p_bytes   = (size_t)CO2 * CMID * 2;
    const size_t zr_bytes    = 2048;
    if (ws_size < featT_bytes + x_bytes + w1p_bytes + w2p_bytes + zr_bytes) return;

    char* ws = (char*)d_ws;
    unsigned short* featT = (unsigned short*)ws;
    unsigned short* xbuf  = (unsigned short*)(ws + featT_bytes);
    unsigned short* w1p   = (unsigned short*)(ws + featT_bytes + x_bytes);
    unsigned short* w2p   = (unsigned short*)(ws + featT_bytes + x_bytes + w1p_bytes);
    unsigned short* zr    = (unsigned short*)(ws + featT_bytes + x_bytes + w1p_bytes + w2p_bytes);

    prep_w_kernel<<<4608, 256, 0, stream>>>(w1, w2, w1p, w2p, (float*)zr);
    transpose_kernel<<<NN * HH, 256, 0, stream>>>(feature, featT);
    conv1_kernel<<<NN * HH, 512, 0, stream>>>(featT, w1p, b1, zr, xbuf);
    conv2_kernel<<<NN * HH * 3, 512, 0, stream>>>(xbuf, w2p, b2, flow, out);
}